// Round 13
// baseline (567.662 us; speedup 1.0000x reference)
//
#include <hip/hip_runtime.h>

#define E_NUM 8
#define FFN_DIM 8192
#define D_DIM 2048
#define T_DIM 4096

using bf16x8 = __attribute__((ext_vector_type(8))) short;
using f32x4  = __attribute__((ext_vector_type(4))) float;
using u16x8  = __attribute__((ext_vector_type(8))) unsigned short;

__device__ __forceinline__ unsigned short f2bf(float f) {
  union { float f; unsigned int u; } v; v.f = f;
  unsigned int u = v.u;
  unsigned int r = (u + 0x7FFFu + ((u >> 16) & 1u)) >> 16;
  return (unsigned short)r;
}

__device__ __forceinline__ void gload16(const unsigned short* g, const unsigned short* l) {
  __builtin_amdgcn_global_load_lds(
      (const __attribute__((address_space(1))) void*)g,
      (__attribute__((address_space(3))) void*)l, 16, 0, 0);
}

// ---------- prep: fp32 -> bf16 convert ----------
__global__ void convert_kernel(const float* __restrict__ src_base,
                               const int* __restrict__ eidx, long slab,
                               unsigned short* __restrict__ dst, long n) {
  const float* src = src_base + (long)(*eidx) * slab;
  long stride = (long)gridDim.x * blockDim.x;
  for (long i = (long)blockIdx.x * blockDim.x + threadIdx.x; i * 8 < n; i += stride) {
    long e = i * 8;
    const float4* p = (const float4*)(src + e);
    float4 f0 = p[0], f1 = p[1];
    u16x8 o;
    o[0] = f2bf(f0.x); o[1] = f2bf(f0.y); o[2] = f2bf(f0.z); o[3] = f2bf(f0.w);
    o[4] = f2bf(f1.x); o[5] = f2bf(f1.y); o[6] = f2bf(f1.z); o[7] = f2bf(f1.w);
    *(u16x8*)(dst + e) = o;
  }
}

// ---------- prep: transpose w2 (FFN,D) fp32 -> (D,FFN) bf16, 64x64 tiles ----------
__global__ __launch_bounds__(512) void transpose_kernel(
    const float* __restrict__ w2, const int* __restrict__ eidx,
    unsigned short* __restrict__ dst) {
  __shared__ unsigned short tile[64][72];
  const float* src = w2 + (long)(*eidx) * (long)FFN_DIM * D_DIM;
  const int tid = threadIdx.x;
  int d0 = blockIdx.x << 6;
  int f0 = blockIdx.y << 6;
#pragma unroll
  for (int p = 0; p < 2; ++p) {
    int f = p * 32 + (tid >> 4);
    int dc = (tid & 15) * 4;
    float4 v = *(const float4*)(src + (long)(f0 + f) * D_DIM + d0 + dc);
    tile[f][dc + 0] = f2bf(v.x); tile[f][dc + 1] = f2bf(v.y);
    tile[f][dc + 2] = f2bf(v.z); tile[f][dc + 3] = f2bf(v.w);
  }
  __syncthreads();
  int d = tid >> 3;
  int fc = (tid & 7) * 8;
  u16x8 o;
#pragma unroll
  for (int j = 0; j < 8; ++j) o[j] = tile[fc + j][d];
  *(u16x8*)(dst + (long)(d0 + d) * FFN_DIM + f0 + fc) = o;
}

#define VMCNT4 asm volatile("s_waitcnt vmcnt(4)" ::: "memory")
#define VMCNT0 asm volatile("s_waitcnt vmcnt(0)" ::: "memory")
// Barrier with lgkm drain (opaque). All reads are consumed in-iter before the
// mid-barrier, so no wave can cross and stage into rows another wave hasn't
// sampled (r5-proven pattern; no read-ahead anywhere).
#define BAR asm volatile("s_waitcnt lgkmcnt(0)\n\ts_barrier" ::: "memory")
#define PRIO1 __builtin_amdgcn_s_setprio(1)
#define PRIO0 __builtin_amdgcn_s_setprio(0)

// ---------- GEMM1 fused: BK=32, 64 KiB LDS -> 2 blocks/CU ----------
// tile 256m x 128n(dual), 8 waves 2Mx4N, wave 128x32 per GEMM.
// Per K-tile: 12 ds_read_b128 + 32 MFMA per wave; stage = 4 gloads (A r0,r1
// each 128 rows; B1; B2). Schedule: {reads; MFMA} BAR {stage(t+2)->cur;
// vmcnt(4)} BAR. Ledger: prologue t0+t1 = 8 out, vmcnt(4) drains t0; per
// iter outstanding 8 -> vmcnt(4) drains t+1 exactly. Tails: t=NT-2 vmcnt(0).
// Swizzle (row stride 32 elem = 64B): slot' = slot ^ ((row>>1)&3) -> 2-way
// max on reads (free); gload dest linear, global source pre-swizzled.
__global__ __launch_bounds__(512, 2) void gemm1_silu(
    const unsigned short* __restrict__ Xb,    // (4096,2048)
    const unsigned short* __restrict__ W1b,   // (8192,2048)
    const unsigned short* __restrict__ V1b,   // (8192,2048)
    unsigned short* __restrict__ Hb) {        // (4096,8192)
  __shared__ __align__(16) unsigned short sA[2 * 8192];    // [buf][256x32]
  __shared__ __align__(16) unsigned short sB1[2 * 4096];   // [buf][128x32]
  __shared__ __align__(16) unsigned short sB2[2 * 4096];

  const int tid = threadIdx.x;
  const int wv = tid >> 6, l = tid & 63;
  const int wm = wv >> 2, wn = wv & 3;        // 2M x 4N
  const int kq = l >> 4, lr = l & 15;
  const int bsw = (blockIdx.x & 7) * 128 + (blockIdx.x >> 3);
  const int m0 = (bsw >> 6) << 8;             // 16 m-blocks
  const int n0 = (bsw & 63) << 7;             // 64 n-blocks

  const int rsub = tid >> 2;                  // 0..127 (row within round)
  const int slotg = ((tid & 3) ^ ((rsub >> 1) & 3)) << 3;  // pre-swizzled col
  const unsigned short* gA  = Xb  + (long)(m0 + rsub) * D_DIM + slotg;
  const unsigned short* gB1 = W1b + (long)(n0 + rsub) * D_DIM + slotg;
  const unsigned short* gB2 = V1b + (long)(n0 + rsub) * D_DIM + slotg;

  // round r_ covers rows [r_*128, r_*128+128); wave wv fills 16 rows linear
#define STG_A(r_, tc_, buf_) \
  gload16(gA + (long)((r_) * 128) * D_DIM + (tc_), sA + (buf_) * 8192 + (r_) * 4096 + wv * 512)
#define STG_B1(tc_, buf_) \
  gload16(gB1 + (tc_), sB1 + (buf_) * 4096 + wv * 512)
#define STG_B2(tc_, buf_) \
  gload16(gB2 + (tc_), sB2 + (buf_) * 4096 + wv * 512)

  int aoffA[4], aoffB[4], boff[2];
#pragma unroll
  for (int j = 0; j < 4; ++j) {
    int rowA = wm * 64 + j * 16 + lr;          // A-half lo: rows 0-127
    aoffA[j] = rowA * 32 + ((kq ^ ((rowA >> 1) & 3)) << 3);
    int rowB = 128 + wm * 64 + j * 16 + lr;    // A-half hi: rows 128-255
    aoffB[j] = rowB * 32 + ((kq ^ ((rowB >> 1) & 3)) << 3);
  }
#pragma unroll
  for (int g = 0; g < 2; ++g) {
    int row = wn * 32 + g * 16 + lr;
    boff[g] = row * 32 + ((kq ^ ((row >> 1) & 3)) << 3);
  }

  f32x4 acc1[8][2], acc2[8][2];
  f32x4 z = {0.f, 0.f, 0.f, 0.f};
#pragma unroll
  for (int f = 0; f < 8; ++f)
#pragma unroll
    for (int g = 0; g < 2; ++g) { acc1[f][g] = z; acc2[f][g] = z; }

  // prologue: stage t0 -> buf0, t1 -> buf1; drain t0 (vmcnt(4)); barrier
  STG_A(0, 0, 0); STG_A(1, 0, 0); STG_B1(0, 0); STG_B2(0, 0);
  STG_A(0, 32, 1); STG_A(1, 32, 1); STG_B1(32, 1); STG_B2(32, 1);
  VMCNT4;
  BAR;

  const int NT = D_DIM / 32;  // 64
  for (int t = 0; t < NT; ++t) {
    const int cur = t & 1;
    const unsigned short* Ac  = sA  + cur * 8192;
    const unsigned short* B1c = sB1 + cur * 4096;
    const unsigned short* B2c = sB2 + cur * 4096;
    bf16x8 aA[4], aB[4], b1[2], b2[2];

    // reads (consumed in-iter by MFMA)
#pragma unroll
    for (int j = 0; j < 4; ++j) {
      aA[j] = *(const bf16x8*)(Ac + aoffA[j]);
      aB[j] = *(const bf16x8*)(Ac + aoffB[j]);
    }
#pragma unroll
    for (int g = 0; g < 2; ++g) {
      b1[g] = *(const bf16x8*)(B1c + boff[g]);
      b2[g] = *(const bf16x8*)(B2c + boff[g]);
    }
    PRIO1;
#pragma unroll
    for (int j = 0; j < 4; ++j)
#pragma unroll
      for (int g = 0; g < 2; ++g) {
        acc1[j][g]     = __builtin_amdgcn_mfma_f32_16x16x32_bf16(aA[j], b1[g], acc1[j][g], 0, 0, 0);
        acc1[4 + j][g] = __builtin_amdgcn_mfma_f32_16x16x32_bf16(aB[j], b1[g], acc1[4 + j][g], 0, 0, 0);
        acc2[j][g]     = __builtin_amdgcn_mfma_f32_16x16x32_bf16(aA[j], b2[g], acc2[j][g], 0, 0, 0);
        acc2[4 + j][g] = __builtin_amdgcn_mfma_f32_16x16x32_bf16(aB[j], b2[g], acc2[4 + j][g], 0, 0, 0);
      }
    PRIO0;
    BAR;   // all waves' reads of cur sampled

    if (t + 2 < NT) {
      const int tc2 = (t + 2) << 5;
      STG_A(0, tc2, cur); STG_A(1, tc2, cur); STG_B1(tc2, cur); STG_B2(tc2, cur);
      VMCNT4;                    // drains exactly tile t+1 (8 out -> 4)
    } else if (t + 1 < NT) {
      VMCNT0;                    // drain tile t+1 for the last iteration
    }
    BAR;
  }

  // epilogue: h = silu(x1)*x2, bf16
#pragma unroll
  for (int f = 0; f < 8; ++f)
#pragma unroll
    for (int g = 0; g < 2; ++g)
#pragma unroll
      for (int r = 0; r < 4; ++r) {
        int row = m0 + (f >> 2) * 128 + wm * 64 + (f & 3) * 16 + kq * 4 + r;
        int col = n0 + wn * 32 + g * 16 + lr;
        float x1 = acc1[f][g][r], x2 = acc2[f][g][r];
        float hv = x1 / (1.f + __expf(-x1)) * x2;
        Hb[(long)row * FFN_DIM + col] = f2bf(hv);
      }
#undef STG_A
#undef STG_B1
#undef STG_B2
}

// ---------- GEMM2: BK=32, tile 128x128, 4 waves, 32 KiB LDS ----------
// 512 blocks (2/CU). Wave 64x64: 8 reads + 16 MFMA per K-tile. Stage = 4
// gloads (A r0,r1; B r0,r1 each 64 rows). Same schedule/ledger as gemm1.
__global__ __launch_bounds__(256, 2) void gemm2(
    const unsigned short* __restrict__ Hb,    // (4096,8192)
    const unsigned short* __restrict__ W2T,   // (2048,8192)
    float* __restrict__ out) {                // (4096,2048)
  __shared__ __align__(16) unsigned short sA[2 * 4096];   // [buf][128x32]
  __shared__ __align__(16) unsigned short sB[2 * 4096];

  const int tid = threadIdx.x;
  const int wv = tid >> 6, l = tid & 63;
  const int wm = wv >> 1, wn = wv & 1;        // 2M x 2N
  const int kq = l >> 4, lr = l & 15;
  const int bsw = (blockIdx.x & 7) * 64 + (blockIdx.x >> 3);   // 512 = 8*64
  const int m0 = (bsw & 31) << 7;             // 32 m-blocks
  const int n0 = (bsw >> 5) << 7;             // 16 n-blocks

  const int rsub = tid >> 2;                  // 0..63
  const int slotg = ((tid & 3) ^ ((rsub >> 1) & 3)) << 3;
  const unsigned short* gA = Hb  + (long)(m0 + rsub) * FFN_DIM + slotg;
  const unsigned short* gB = W2T + (long)(n0 + rsub) * FFN_DIM + slotg;

#define STG_A(r_, tc_, buf_) \
  gload16(gA + (long)((r_) * 64) * FFN_DIM + (tc_), sA + (buf_) * 4096 + (r_) * 2048 + wv * 512)
#define STG_B(r_, tc_, buf_) \
  gload16(gB + (long)((r_) * 64) * FFN_DIM + (tc_), sB + (buf_) * 4096 + (r_) * 2048 + wv * 512)

  int aoff[4], boff[4];
#pragma unroll
  for (int f = 0; f < 4; ++f) {
    int row = wm * 64 + f * 16 + lr;
    aoff[f] = row * 32 + ((kq ^ ((row >> 1) & 3)) << 3);
  }
#pragma unroll
  for (int g = 0; g < 4; ++g) {
    int row = wn * 64 + g * 16 + lr;
    boff[g] = row * 32 + ((kq ^ ((row >> 1) & 3)) << 3);
  }

  f32x4 acc[4][4];
  f32x4 z = {0.f, 0.f, 0.f, 0.f};
#pragma unroll
  for (int f = 0; f < 4; ++f)
#pragma unroll
    for (int g = 0; g < 4; ++g) acc[f][g] = z;

  // prologue: t0 -> buf0, t1 -> buf1; vmcnt(4) drains t0
  STG_A(0, 0, 0); STG_A(1, 0, 0); STG_B(0, 0, 0); STG_B(1, 0, 0);
  STG_A(0, 32, 1); STG_A(1, 32, 1); STG_B(0, 32, 1); STG_B(1, 32, 1);
  VMCNT4;
  BAR;

  const int NT = FFN_DIM / 32;  // 256
  for (int t = 0; t < NT; ++t) {
    const int cur = t & 1;
    const unsigned short* Ac = sA + cur * 4096;
    const unsigned short* Bc = sB + cur * 4096;
    bf16x8 af[4], bf_[4];

#pragma unroll
    for (int f = 0; f < 4; ++f) af[f] = *(const bf16x8*)(Ac + aoff[f]);
#pragma unroll
    for (int g = 0; g < 4; ++g) bf_[g] = *(const bf16x8*)(Bc + boff[g]);
    PRIO1;
#pragma unroll
    for (int f = 0; f < 4; ++f)
#pragma unroll
      for (int g = 0; g < 4; ++g)
        acc[f][g] = __builtin_amdgcn_mfma_f32_16x16x32_bf16(af[f], bf_[g], acc[f][g], 0, 0, 0);
    PRIO0;
    BAR;

    if (t + 2 < NT) {
      const int tc2 = (t + 2) << 5;
      STG_A(0, tc2, cur); STG_A(1, tc2, cur); STG_B(0, tc2, cur); STG_B(1, tc2, cur);
      VMCNT4;
    } else if (t + 1 < NT) {
      VMCNT0;
    }
    BAR;
  }

#pragma unroll
  for (int f = 0; f < 4; ++f)
#pragma unroll
    for (int g = 0; g < 4; ++g)
#pragma unroll
      for (int r = 0; r < 4; ++r) {
        int row = m0 + wm * 64 + f * 16 + kq * 4 + r;
        int col = n0 + wn * 64 + g * 16 + lr;
        out[(long)row * D_DIM + col] = acc[f][g][r];
      }
#undef STG_A
#undef STG_B
}

extern "C" void kernel_launch(void* const* d_in, const int* in_sizes, int n_in,
                              void* d_out, int out_size, void* d_ws, size_t ws_size,
                              hipStream_t stream) {
  const float* x  = (const float*)d_in[0];
  const float* w1 = (const float*)d_in[1];
  const float* v1 = (const float*)d_in[2];
  const float* w2 = (const float*)d_in[3];
  const int* eidx = (const int*)d_in[4];

  char* ws = (char*)d_ws;
  unsigned short* Xb  = (unsigned short*)(ws);                  // 16 MiB
  unsigned short* W1b = (unsigned short*)(ws + (16l << 20));    // 32 MiB
  unsigned short* V1b = (unsigned short*)(ws + (48l << 20));    // 32 MiB
  unsigned short* W2T = (unsigned short*)(ws + (80l << 20));    // 32 MiB
  unsigned short* Hb  = (unsigned short*)(ws + (112l << 20));   // 64 MiB
  float* out = (float*)d_out;

  long slab = (long)FFN_DIM * D_DIM;
  transpose_kernel<<<dim3(D_DIM / 64, FFN_DIM / 64), 512, 0, stream>>>(w2, eidx, W2T);
  convert_kernel<<<2048, 256, 0, stream>>>(w1, eidx, slab, W1b, slab);
  convert_kernel<<<2048, 256, 0, stream>>>(v1, eidx, slab, V1b, slab);
  convert_kernel<<<2048, 256, 0, stream>>>(x,  eidx, 0,    Xb,  (long)T_DIM * D_DIM);
  gemm1_silu<<<1024, 512, 0, stream>>>(Xb, W1b, V1b, Hb);
  gemm2<<<512, 256, 0, stream>>>(Hb, W2T, out);
}

// Round 14
// 494.466 us; speedup vs baseline: 1.1480x; 1.1480x over previous
//
#include <hip/hip_runtime.h>

#define E_NUM 8
#define FFN_DIM 8192
#define D_DIM 2048
#define T_DIM 4096

using bf16x8 = __attribute__((ext_vector_type(8))) short;
using f32x4  = __attribute__((ext_vector_type(4))) float;
using u16x8  = __attribute__((ext_vector_type(8))) unsigned short;

__device__ __forceinline__ unsigned short f2bf(float f) {
  union { float f; unsigned int u; } v; v.f = f;
  unsigned int u = v.u;
  unsigned int r = (u + 0x7FFFu + ((u >> 16) & 1u)) >> 16;
  return (unsigned short)r;
}

__device__ __forceinline__ void gload16(const unsigned short* g, const unsigned short* l) {
  __builtin_amdgcn_global_load_lds(
      (const __attribute__((address_space(1))) void*)g,
      (__attribute__((address_space(3))) void*)l, 16, 0, 0);
}

// ---------- prep: fp32 -> bf16 convert ----------
__global__ void convert_kernel(const float* __restrict__ src_base,
                               const int* __restrict__ eidx, long slab,
                               unsigned short* __restrict__ dst, long n) {
  const float* src = src_base + (long)(*eidx) * slab;
  long stride = (long)gridDim.x * blockDim.x;
  for (long i = (long)blockIdx.x * blockDim.x + threadIdx.x; i * 8 < n; i += stride) {
    long e = i * 8;
    const float4* p = (const float4*)(src + e);
    float4 f0 = p[0], f1 = p[1];
    u16x8 o;
    o[0] = f2bf(f0.x); o[1] = f2bf(f0.y); o[2] = f2bf(f0.z); o[3] = f2bf(f0.w);
    o[4] = f2bf(f1.x); o[5] = f2bf(f1.y); o[6] = f2bf(f1.z); o[7] = f2bf(f1.w);
    *(u16x8*)(dst + e) = o;
  }
}

// ---------- prep: transpose w2 (FFN,D) fp32 -> (D,FFN) bf16, 64x64 tiles ----------
__global__ __launch_bounds__(512) void transpose_kernel(
    const float* __restrict__ w2, const int* __restrict__ eidx,
    unsigned short* __restrict__ dst) {
  __shared__ unsigned short tile[64][72];
  const float* src = w2 + (long)(*eidx) * (long)FFN_DIM * D_DIM;
  const int tid = threadIdx.x;
  int d0 = blockIdx.x << 6;
  int f0 = blockIdx.y << 6;
#pragma unroll
  for (int p = 0; p < 2; ++p) {
    int f = p * 32 + (tid >> 4);
    int dc = (tid & 15) * 4;
    float4 v = *(const float4*)(src + (long)(f0 + f) * D_DIM + d0 + dc);
    tile[f][dc + 0] = f2bf(v.x); tile[f][dc + 1] = f2bf(v.y);
    tile[f][dc + 2] = f2bf(v.z); tile[f][dc + 3] = f2bf(v.w);
  }
  __syncthreads();
  int d = tid >> 3;
  int fc = (tid & 7) * 8;
  u16x8 o;
#pragma unroll
  for (int j = 0; j < 8; ++j) o[j] = tile[fc + j][d];
  *(u16x8*)(dst + (long)(d0 + d) * FFN_DIM + f0 + fc) = o;
}

#define VMCNT6 asm volatile("s_waitcnt vmcnt(6)" ::: "memory")
#define VMCNT3 asm volatile("s_waitcnt vmcnt(3)" ::: "memory")
#define VMCNT0 asm volatile("s_waitcnt vmcnt(0)" ::: "memory")
#define BARX  asm volatile("s_barrier" ::: "memory")
#define LGKM0 asm volatile("s_waitcnt lgkmcnt(0)" ::: "memory")
// drain-barrier (r11-proven) for gemm2 and epilogue exchange
#define BARD asm volatile("s_waitcnt lgkmcnt(0)\n\ts_barrier" ::: "memory")
#define PRIO1 __builtin_amdgcn_s_setprio(1)
#define PRIO0 __builtin_amdgcn_s_setprio(0)

// ---------- GEMM1 fused: TRUE 8-phase template (m201), dual-B 256x256 ----------
// B-tile rows = [128 W1-rows | 128 V1-rows] of the SAME 128 FFN cols.
// BK=64, 8 waves 2Mx4N, per-wave 128x64. LDS 128KB: sA/sB = 2dbuf x 256x64.
// Fixed parity: even K-tiles -> dbuf0, odd -> dbuf1.
// Per iter (tiles t=2i cur, t'=2i+1 nxt), 8 phases; phase = {reads; 1-half
// stage; BARX; LGKM0; 16 MFMA (setprio); BARX}. vmcnt(6) at P4/P8 only.
// Stage slots (ledger-audited): P1:nxt.A1(t') P3:cur.B0(t+2) P4:cur.B1+A0(t+2)
// P5:cur.A1(t+2) P7:nxt.B0(t+3) P8:nxt.B1+A0(t+3).
//  - landed: tile reads at P1 staged prev P3-P5 (drained by prev P8 vmcnt6);
//    reads at P5 staged prev P7,P8,this P1 (drained by this P4 vmcnt6).
//  - WAR: cur.B read P1-P2 (stage P3+); cur.A read P1,P3 (stage P4+);
//    nxt.B read P5-P6 (stage P7+); nxt.A read P5,P7 (stage P8+). All reads
//    drained in-phase (LGKM0 before MFMA) before trailing barrier.
// Epilogue: wn>=2 waves write x2 (f32) to LDS; wn<2 combine silu(x1)*x2.
__global__ __launch_bounds__(512, 2) void gemm1_silu(
    const unsigned short* __restrict__ Xb,    // (4096,2048)
    const unsigned short* __restrict__ W1b,   // (8192,2048)
    const unsigned short* __restrict__ V1b,   // (8192,2048)
    unsigned short* __restrict__ Hb) {        // (4096,8192)
  __shared__ __align__(16) unsigned short lds[65536];   // 128 KiB
  unsigned short* sA = lds;            // [dbuf][256*64]
  unsigned short* sB = lds + 32768;

  const int tid = threadIdx.x;
  const int wv = tid >> 6, l = tid & 63;
  const int wm = wv >> 2, wn = wv & 3;        // 2M x 4N
  const int kq = l >> 4, lr = l & 15;
  const int bsw = (blockIdx.x & 7) * 128 + (blockIdx.x >> 3);
  const int m0 = (bsw >> 6) << 8;             // 16 m-blocks (256 rows)
  const int ffn0 = (bsw & 63) << 7;           // 64 n-blocks (128 FFN cols)

  const int rsub = tid >> 3;                  // 0..63
  const int slotg = ((tid & 7) ^ (rsub & 7)) << 3;   // pre-swizzled col
  const unsigned short* gA  = Xb  + (long)(m0 + rsub) * D_DIM + slotg;
  const unsigned short* gB1 = W1b + (long)(ffn0 + rsub) * D_DIM + slotg;
  const unsigned short* gB2 = V1b + (long)(ffn0 + rsub) * D_DIM + slotg;

  // one 64-row round; half-tile = 2 rounds
#define SGA(db, h, r_, tc_) \
  gload16(gA + (long)((h) * 128 + (r_) * 64) * D_DIM + (tc_), \
          sA + (db) * 16384 + (h) * 8192 + (r_) * 4096 + wv * 512)
#define SGB1(db, r_, tc_) \
  gload16(gB1 + (long)((r_) * 64) * D_DIM + (tc_), \
          sB + (db) * 16384 + (r_) * 4096 + wv * 512)
#define SGB2(db, r_, tc_) \
  gload16(gB2 + (long)((r_) * 64) * D_DIM + (tc_), \
          sB + (db) * 16384 + 8192 + (r_) * 4096 + wv * 512)

  int aoff[8], boff[4];
#pragma unroll
  for (int j = 0; j < 8; ++j) {
    int row = wm * 128 + j * 16 + lr;
    aoff[j] = row * 64 + ((kq ^ (row & 7)) << 3);
  }
#pragma unroll
  for (int n = 0; n < 4; ++n) {
    int row = wn * 64 + n * 16 + lr;
    boff[n] = row * 64 + ((kq ^ (row & 7)) << 3);
  }

  f32x4 acc[8][4];
  f32x4 z = {0.f, 0.f, 0.f, 0.f};
#pragma unroll
  for (int j = 0; j < 8; ++j)
#pragma unroll
    for (int n = 0; n < 4; ++n) acc[j][n] = z;

  bf16x8 aX[4][2], bLo[2][2], bHi[2][2];

  // prologue: tile0 -> dbuf0 (4 halves), tile1 -> dbuf1 {B0,B1,A0}; vmcnt(6)
  SGB1(0, 0, 0); SGB1(0, 1, 0);
  SGB2(0, 0, 0); SGB2(0, 1, 0);
  SGA(0, 0, 0, 0); SGA(0, 0, 1, 0);
  SGA(0, 1, 0, 0); SGA(0, 1, 1, 0);
  SGB1(1, 0, 64); SGB1(1, 1, 64);
  SGB2(1, 0, 64); SGB2(1, 1, 64);
  SGA(1, 0, 0, 64); SGA(1, 0, 1, 64);
  VMCNT6;
  BARX;

#define RD_A(J0, base) \
  _Pragma("unroll") for (int j = 0; j < 4; ++j) { \
    aX[j][0] = *(const bf16x8*)((base) + aoff[(J0) + j]); \
    aX[j][1] = *(const bf16x8*)((base) + (aoff[(J0) + j] ^ 32)); }
#define RD_B(dst, N0, base) \
  _Pragma("unroll") for (int n = 0; n < 2; ++n) { \
    dst[n][0] = *(const bf16x8*)((base) + boff[(N0) + n]); \
    dst[n][1] = *(const bf16x8*)((base) + (boff[(N0) + n] ^ 32)); }
#define MFMA_Q(J0, N0, br) \
  PRIO1; \
  _Pragma("unroll") for (int j = 0; j < 4; ++j) \
  _Pragma("unroll") for (int n = 0; n < 2; ++n) { \
    acc[(J0)+j][(N0)+n] = __builtin_amdgcn_mfma_f32_16x16x32_bf16(aX[j][0], br[n][0], acc[(J0)+j][(N0)+n], 0, 0, 0); \
    acc[(J0)+j][(N0)+n] = __builtin_amdgcn_mfma_f32_16x16x32_bf16(aX[j][1], br[n][1], acc[(J0)+j][(N0)+n], 0, 0, 0); } \
  PRIO0;

  const int NITER = D_DIM / 128;  // 16 (2 K-tiles per iter)
  for (int i = 0; i < NITER; ++i) {
    const unsigned short* cA = sA;            // dbuf0 (even tiles)
    const unsigned short* cB = sB;
    const unsigned short* nA = sA + 16384;    // dbuf1 (odd tiles)
    const unsigned short* nB = sB + 16384;
    const int tcn = (2 * i + 1) << 6;
    const int tc2 = (2 * i + 2) << 6;
    const int tc3 = (2 * i + 3) << 6;
    const int st2 = (2 * i + 2 < 32), st3 = (2 * i + 3 < 32);

    // ---- P1: read cur A j0-3 + B n0-1; stage nxt.A1(t'); Q(0,0) ----
    RD_A(0, cA); RD_B(bLo, 0, cB);
    SGA(1, 1, 0, tcn); SGA(1, 1, 1, tcn);
    BARX; LGKM0;
    MFMA_Q(0, 0, bLo);
    BARX;

    // ---- P2: read cur B n2-3; Q(0,1) ----
    RD_B(bHi, 2, cB);
    BARX; LGKM0;
    MFMA_Q(0, 2, bHi);
    BARX;

    // ---- P3: read cur A j4-7; stage cur.B0(t+2); Q(1,1) ----
    RD_A(4, cA);
    if (st2) { SGB1(0, 0, tc2); SGB1(0, 1, tc2); }
    BARX; LGKM0;
    MFMA_Q(4, 2, bHi);
    BARX;

    // ---- P4: stage cur.B1+A0(t+2); Q(1,0); vmcnt(6) ----
    if (st2) { SGB2(0, 0, tc2); SGB2(0, 1, tc2); SGA(0, 0, 0, tc2); SGA(0, 0, 1, tc2); }
    BARX;
    MFMA_Q(4, 0, bLo);
    if (st2) { VMCNT6; } else { VMCNT0; }
    BARX;

    // ---- P5: read nxt A j0-3 + B n0-1; stage cur.A1(t+2); Q(0,0) ----
    RD_A(0, nA); RD_B(bLo, 0, nB);
    if (st2) { SGA(0, 1, 0, tc2); SGA(0, 1, 1, tc2); }
    BARX; LGKM0;
    MFMA_Q(0, 0, bLo);
    BARX;

    // ---- P6: read nxt B n2-3; Q(0,1) ----
    RD_B(bHi, 2, nB);
    BARX; LGKM0;
    MFMA_Q(0, 2, bHi);
    BARX;

    // ---- P7: read nxt A j4-7; stage nxt.B0(t+3); Q(1,1) ----
    RD_A(4, nA);
    if (st3) { SGB1(1, 0, tc3); SGB1(1, 1, tc3); }
    BARX; LGKM0;
    MFMA_Q(4, 2, bHi);
    BARX;

    // ---- P8: stage nxt.B1+A0(t+3); Q(1,0); vmcnt(6) ----
    if (st3) { SGB2(1, 0, tc3); SGB2(1, 1, tc3); SGA(1, 0, 0, tc3); SGA(1, 0, 1, tc3); }
    BARX;
    MFMA_Q(4, 0, bLo);
    if (st3) { VMCNT6; } else { VMCNT0; }
    BARX;
  }

  // ---- epilogue: exchange x2 via LDS, fuse silu, store bf16 ----
  float* xls = (float*)lds;   // 128KB = 4 waves x 128x64 f32
  if (wn >= 2) {
    const int base = (wm * 2 + (wn - 2)) * 8192;
#pragma unroll
    for (int j = 0; j < 8; ++j)
#pragma unroll
      for (int n = 0; n < 4; ++n)
#pragma unroll
        for (int r = 0; r < 4; ++r)
          xls[base + (j * 16 + kq * 4 + r) * 64 + n * 16 + lr] = acc[j][n][r];
  }
  BARD;
  if (wn < 2) {
    const int base = (wm * 2 + wn) * 8192;
#pragma unroll
    for (int j = 0; j < 8; ++j)
#pragma unroll
      for (int n = 0; n < 4; ++n)
#pragma unroll
        for (int r = 0; r < 4; ++r) {
          float x1 = acc[j][n][r];
          float x2 = xls[base + (j * 16 + kq * 4 + r) * 64 + n * 16 + lr];
          float hv = x1 / (1.f + __expf(-x1)) * x2;
          int row = m0 + wm * 128 + j * 16 + kq * 4 + r;
          int col = ffn0 + wn * 64 + n * 16 + lr;
          Hb[(long)row * FFN_DIM + col] = f2bf(hv);
        }
  }
#undef SGA
#undef SGB1
#undef SGB2
#undef RD_A
#undef RD_B
#undef MFMA_Q
}

// ---------- GEMM2 (r11-proven): read-ahead 4-phase, 256x128, BK=64 ----------
__global__ __launch_bounds__(512, 2) void gemm2(
    const unsigned short* __restrict__ Hb,    // (4096,8192)
    const unsigned short* __restrict__ W2T,   // (2048,8192)
    float* __restrict__ out) {                // (4096,2048)
  __shared__ __align__(16) unsigned short sA[2 * 16384];
  __shared__ __align__(16) unsigned short sB[2 * 8192];

  const int tid = threadIdx.x;
  const int wv = tid >> 6, l = tid & 63;
  const int wm = wv >> 1, wn = wv & 1;
  const int kq = l >> 4, lr = l & 15;
  const int bsw = (blockIdx.x & 7) * 32 + (blockIdx.x >> 3);
  const int m0 = (bsw >> 4) << 8;
  const int n0 = (bsw & 15) << 7;

  const int rsub = tid >> 3;
  const int sslot8 = ((tid & 7) ^ ((tid >> 3) & 7)) << 3;
  const unsigned short* gA = Hb  + (long)(m0 + rsub) * FFN_DIM + sslot8;
  const unsigned short* gB = W2T + (long)(n0 + rsub) * FFN_DIM + sslot8;

#define STG1(gbase, r_, tc_, lbase) \
  gload16((gbase) + (long)((r_) * 64) * FFN_DIM + (tc_), (lbase) + (r_) * 4096 + wv * 512)

  int aoff[4], boff[4];
#pragma unroll
  for (int f = 0; f < 4; ++f) {
    int row = wm * 64 + f * 16 + lr;
    aoff[f] = row * 64 + ((kq ^ (row & 7)) << 3);
  }
#pragma unroll
  for (int g = 0; g < 4; ++g) {
    int row = wn * 64 + g * 16 + lr;
    boff[g] = row * 64 + ((kq ^ (row & 7)) << 3);
  }

  f32x4 acc[4][4];
  f32x4 z = {0.f, 0.f, 0.f, 0.f};
#pragma unroll
  for (int f = 0; f < 4; ++f)
#pragma unroll
    for (int g = 0; g < 4; ++g) acc[f][g] = z;

  bf16x8 aA[2][2], aB[2][2], bA[2][2], bB[2][2];

  STG1(gB, 0, 0, sB); STG1(gB, 1, 0, sB);
  STG1(gA, 0, 0, sA); STG1(gA, 1, 0, sA); STG1(gA, 2, 0, sA); STG1(gA, 3, 0, sA);
  STG1(gB, 0, 64, sB + 8192); STG1(gB, 1, 64, sB + 8192);
  STG1(gA, 0, 64, sA + 16384); STG1(gA, 1, 64, sA + 16384);
  STG1(gA, 2, 64, sA + 16384); STG1(gA, 3, 64, sA + 16384);
  VMCNT6;
  BARD;
#pragma unroll
  for (int f = 0; f < 2; ++f) {
    aA[f][0] = *(const bf16x8*)(sA + aoff[f]);
    aA[f][1] = *(const bf16x8*)(sA + (aoff[f] ^ 32));
  }
#pragma unroll
  for (int g = 0; g < 2; ++g) {
    bA[g][0] = *(const bf16x8*)(sB + boff[g]);
    bA[g][1] = *(const bf16x8*)(sB + (boff[g] ^ 32));
  }
  BARD;   // pre-reads sampled before any loop stage (r11 race fix)

  const int NT = FFN_DIM / 64;  // 128
  for (int t = 0; t < NT; ++t) {
    const int db = t & 1, nx = db ^ 1;
    const unsigned short* Acur = sA + db * 16384;
    const unsigned short* Anxt = sA + nx * 16384;
    const unsigned short* Bcur = sB + db * 8192;
    const unsigned short* Bnxt = sB + nx * 8192;
    unsigned short* AcurW = (unsigned short*)sA + db * 16384;
    unsigned short* BcurW = (unsigned short*)sB + db * 8192;
    const int p1ok = (t + 1 < NT), p2ok = (t + 2 < NT);
    const int tc2 = (t + 2) << 6;

#pragma unroll
    for (int f = 0; f < 2; ++f) {
      aB[f][0] = *(const bf16x8*)(Acur + aoff[2 + f]);
      aB[f][1] = *(const bf16x8*)(Acur + (aoff[2 + f] ^ 32));
    }
#pragma unroll
    for (int g = 0; g < 2; ++g) {
      bB[g][0] = *(const bf16x8*)(Bcur + boff[2 + g]);
      bB[g][1] = *(const bf16x8*)(Bcur + (boff[2 + g] ^ 32));
    }
    PRIO1;
#pragma unroll
    for (int f = 0; f < 2; ++f)
#pragma unroll
      for (int g = 0; g < 2; ++g) {
        acc[f][g] = __builtin_amdgcn_mfma_f32_16x16x32_bf16(aA[f][0], bA[g][0], acc[f][g], 0, 0, 0);
        acc[f][g] = __builtin_amdgcn_mfma_f32_16x16x32_bf16(aA[f][1], bA[g][1], acc[f][g], 0, 0, 0);
      }
    PRIO0;
    BARD;

    if (p2ok) { STG1(gB, 0, tc2, BcurW); STG1(gB, 1, tc2, BcurW); STG1(gA, 0, tc2, AcurW); }
    PRIO1;
#pragma unroll
    for (int f = 0; f < 2; ++f)
#pragma unroll
      for (int g = 0; g < 2; ++g) {
        acc[2 + f][g] = __builtin_amdgcn_mfma_f32_16x16x32_bf16(aB[f][0], bA[g][0], acc[2 + f][g], 0, 0, 0);
        acc[2 + f][g] = __builtin_amdgcn_mfma_f32_16x16x32_bf16(aB[f][1], bA[g][1], acc[2 + f][g], 0, 0, 0);
      }
    PRIO0;
    if (p2ok) { VMCNT3; } else if (p1ok) { VMCNT0; }
    BARD;

    if (p2ok) { STG1(gA, 1, tc2, AcurW); STG1(gA, 2, tc2, AcurW); STG1(gA, 3, tc2, AcurW); }
    PRIO1;
#pragma unroll
    for (int f = 0; f < 2; ++f)
#pragma unroll
      for (int g = 0; g < 2; ++g) {
        acc[f][2 + g] = __builtin_amdgcn_mfma_f32_16x16x32_bf16(aA[f][0], bB[g][0], acc[f][2 + g], 0, 0, 0);
        acc[f][2 + g] = __builtin_amdgcn_mfma_f32_16x16x32_bf16(aA[f][1], bB[g][1], acc[f][2 + g], 0, 0, 0);
      }
    PRIO0;
    if (p1ok) {
#pragma unroll
      for (int f = 0; f < 2; ++f) {
        aA[f][0] = *(const bf16x8*)(Anxt + aoff[f]);
        aA[f][1] = *(const bf16x8*)(Anxt + (aoff[f] ^ 32));
      }
    }
    BARD;

    PRIO1;
#pragma unroll
    for (int f = 0; f < 2; ++f)
#pragma unroll
      for (int g = 0; g < 2; ++g) {
        acc[2 + f][2 + g] = __builtin_amdgcn_mfma_f32_16x16x32_bf16(aB[f][0], bB[g][0], acc[2 + f][2 + g], 0, 0, 0);
        acc[2 + f][2 + g] = __builtin_amdgcn_mfma_f32_16x16x32_bf16(aB[f][1], bB[g][1], acc[2 + f][2 + g], 0, 0, 0);
      }
    PRIO0;
    if (p1ok) {
#pragma unroll
      for (int g = 0; g < 2; ++g) {
        bA[g][0] = *(const bf16x8*)(Bnxt + boff[g]);
        bA[g][1] = *(const bf16x8*)(Bnxt + (boff[g] ^ 32));
      }
    }
    BARD;
  }

#pragma unroll
  for (int f = 0; f < 4; ++f)
#pragma unroll
    for (int g = 0; g < 4; ++g)
#pragma unroll
      for (int r = 0; r < 4; ++r) {
        int row = m0 + wm * 64 + f * 16 + kq * 4 + r;
        int col = n0 + wn * 64 + g * 16 + lr;
        out[(long)row * D_DIM + col] = acc[f][g][r];
      }
#undef STG1
}

extern "C" void kernel_launch(void* const* d_in, const int* in_sizes, int n_in,
                              void* d_out, int out_size, void* d_ws, size_t ws_size,
                              hipStream_t stream) {
  const float* x  = (const float*)d_in[0];
  const float* w1 = (const float*)d_in[1];
  const float* v1 = (const float*)d_in[2];
  const float* w2 = (const float*)d_in[3];
  const int* eidx = (const int*)d_in[4];

  char* ws = (char*)d_ws;
  unsigned short* Xb  = (unsigned short*)(ws);                  // 16 MiB
  unsigned short* W1b = (unsigned short*)(ws + (16l << 20));    // 32 MiB
  unsigned short* V1b = (unsigned short*)(ws + (48l << 20));    // 32 MiB
  unsigned short* W2T = (unsigned short*)(ws + (80l << 20));    // 32 MiB
  unsigned short* Hb  = (unsigned short*)(ws + (112l << 20));   // 64 MiB
  float* out = (float*)d_out;

  long slab = (long)FFN_DIM * D_DIM;
  transpose_kernel<<<dim3(D_DIM / 64, FFN_DIM / 64), 512, 0, stream>>>(w2, eidx, W2T);
  convert_kernel<<<2048, 256, 0, stream>>>(w1, eidx, slab, W1b, slab);
  convert_kernel<<<2048, 256, 0, stream>>>(v1, eidx, slab, V1b, slab);
  convert_kernel<<<2048, 256, 0, stream>>>(x,  eidx, 0,    Xb,  (long)T_DIM * D_DIM);
  gemm1_silu<<<1024, 512, 0, stream>>>(Xb, W1b, V1b, Hb);
  gemm2<<<256, 512, 0, stream>>>(Hb, W2T, out);
}

// Round 15
// 481.810 us; speedup vs baseline: 1.1782x; 1.0263x over previous
//
#include <hip/hip_runtime.h>

#define E_NUM 8
#define FFN_DIM 8192
#define D_DIM 2048
#define T_DIM 4096

using bf16x8 = __attribute__((ext_vector_type(8))) short;
using f32x4  = __attribute__((ext_vector_type(4))) float;
using u16x8  = __attribute__((ext_vector_type(8))) unsigned short;

__device__ __forceinline__ unsigned short f2bf(float f) {
  union { float f; unsigned int u; } v; v.f = f;
  unsigned int u = v.u;
  unsigned int r = (u + 0x7FFFu + ((u >> 16) & 1u)) >> 16;
  return (unsigned short)r;
}

__device__ __forceinline__ void gload16(const unsigned short* g, const unsigned short* l) {
  __builtin_amdgcn_global_load_lds(
      (const __attribute__((address_space(1))) void*)g,
      (__attribute__((address_space(3))) void*)l, 16, 0, 0);
}

// ---------- prep: merged fp32 -> bf16 convert (w1 | v1 | x via blockIdx.y) ----------
__global__ void convert3_kernel(const float* __restrict__ x,
                                const float* __restrict__ w1,
                                const float* __restrict__ v1,
                                const int* __restrict__ eidx,
                                unsigned short* __restrict__ Xb,
                                unsigned short* __restrict__ W1b,
                                unsigned short* __restrict__ V1b) {
  const long slab = (long)FFN_DIM * D_DIM;
  const float* src;
  unsigned short* dst;
  long n;
  if (blockIdx.y == 0)      { src = w1 + (long)(*eidx) * slab; dst = W1b; n = slab; }
  else if (blockIdx.y == 1) { src = v1 + (long)(*eidx) * slab; dst = V1b; n = slab; }
  else                      { src = x;                          dst = Xb;  n = (long)T_DIM * D_DIM; }
  long stride = (long)gridDim.x * blockDim.x;
  for (long i = (long)blockIdx.x * blockDim.x + threadIdx.x; i * 8 < n; i += stride) {
    long e = i * 8;
    const float4* p = (const float4*)(src + e);
    float4 f0 = p[0], f1 = p[1];
    u16x8 o;
    o[0] = f2bf(f0.x); o[1] = f2bf(f0.y); o[2] = f2bf(f0.z); o[3] = f2bf(f0.w);
    o[4] = f2bf(f1.x); o[5] = f2bf(f1.y); o[6] = f2bf(f1.z); o[7] = f2bf(f1.w);
    *(u16x8*)(dst + e) = o;
  }
}

// ---------- prep: transpose w2 (FFN,D) fp32 -> (D,FFN) bf16, 64x64 tiles ----------
__global__ __launch_bounds__(512) void transpose_kernel(
    const float* __restrict__ w2, const int* __restrict__ eidx,
    unsigned short* __restrict__ dst) {
  __shared__ unsigned short tile[64][72];
  const float* src = w2 + (long)(*eidx) * (long)FFN_DIM * D_DIM;
  const int tid = threadIdx.x;
  int d0 = blockIdx.x << 6;
  int f0 = blockIdx.y << 6;
#pragma unroll
  for (int p = 0; p < 2; ++p) {
    int f = p * 32 + (tid >> 4);
    int dc = (tid & 15) * 4;
    float4 v = *(const float4*)(src + (long)(f0 + f) * D_DIM + d0 + dc);
    tile[f][dc + 0] = f2bf(v.x); tile[f][dc + 1] = f2bf(v.y);
    tile[f][dc + 2] = f2bf(v.z); tile[f][dc + 3] = f2bf(v.w);
  }
  __syncthreads();
  int d = tid >> 3;
  int fc = (tid & 7) * 8;
  u16x8 o;
#pragma unroll
  for (int j = 0; j < 8; ++j) o[j] = tile[fc + j][d];
  *(u16x8*)(dst + (long)(d0 + d) * FFN_DIM + f0 + fc) = o;
}

// Counted vmcnt waits with memory clobber (stage issues pinned to their side
// of the wait so the outstanding-count arithmetic stays exact — r8/r9 lesson).
#define VMCNT6 asm volatile("s_waitcnt vmcnt(6)" ::: "memory")
#define VMCNT5 asm volatile("s_waitcnt vmcnt(5)" ::: "memory")
#define VMCNT3 asm volatile("s_waitcnt vmcnt(3)" ::: "memory")
#define VMCNT0 asm volatile("s_waitcnt vmcnt(0)" ::: "memory")
// Barrier = lgkmcnt(0) drain + s_barrier (opaque). Invariant: a ds_read and a
// later global_load_lds stage overwriting the same LDS rows must be separated
// by one of these — the drain guarantees the read sampled LDS before any wave
// crosses and issues the overwrite (r7-r10 lesson). vmcnt NOT drained here.
#define BAR asm volatile("s_waitcnt lgkmcnt(0)\n\ts_barrier" ::: "memory")
#define PRIO1 __builtin_amdgcn_s_setprio(1)
#define PRIO0 __builtin_amdgcn_s_setprio(0)

// ---------- GEMM1 fused, read-ahead pipelined 4-phase (r11-proven) ----------
// tile 256m x 128n(dual), BK=64, 8 waves 2Mx4N, wave 128x32 per GEMM.
// Frag reads >=1 phase ahead of MFMA use: aA(t)@p3(t-1), b1(t)@p4(t-1),
// aB(t)@p1(t), b2(t)@p2(t).
// Stages for t+2 (8 rounds): B1x2@p1, Ax3@p2, Ax1+B2x2@p3.
// One vmcnt(5)@p2 drains exactly tile t+1 (peak 13 outstanding -> 5).
// Prologue pre-reads followed by BAR (race fix: sampled before first stage).
// launch_bounds (512,1): LDS=128KB caps at 1 block/CU anyway; uncapped VGPR
// gives the scheduler pipelining headroom.
__global__ __launch_bounds__(512, 1) void gemm1_silu(
    const unsigned short* __restrict__ Xb,    // (4096,2048)
    const unsigned short* __restrict__ W1b,   // (8192,2048)
    const unsigned short* __restrict__ V1b,   // (8192,2048)
    unsigned short* __restrict__ Hb) {        // (4096,8192)
  __shared__ __align__(16) unsigned short sA[2 * 16384];   // 256x64 per buf
  __shared__ __align__(16) unsigned short sB1[2 * 8192];   // 128x64
  __shared__ __align__(16) unsigned short sB2[2 * 8192];

  const int tid = threadIdx.x;
  const int wv = tid >> 6, l = tid & 63;
  const int wm = wv >> 2, wn = wv & 3;        // 2M x 4N
  const int kq = l >> 4, lr = l & 15;
  const int bsw = (blockIdx.x & 7) * 128 + (blockIdx.x >> 3);
  const int m0 = (bsw >> 6) << 8;             // 16 m-blocks
  const int n0 = (bsw & 63) << 7;             // 64 n-blocks

  const int rsub = tid >> 3;
  const int sslot8 = ((tid & 7) ^ ((tid >> 3) & 7)) << 3;
  const unsigned short* gA  = Xb  + (long)(m0 + rsub) * D_DIM + sslot8;
  const unsigned short* gB1 = W1b + (long)(n0 + rsub) * D_DIM + sslot8;
  const unsigned short* gB2 = V1b + (long)(n0 + rsub) * D_DIM + sslot8;

#define STG1(gbase, r_, tc_, lbase) \
  gload16((gbase) + (long)((r_) * 64) * D_DIM + (tc_), (lbase) + (r_) * 4096 + wv * 512)

  int aoffA[4], aoffB[4], boff[2];
#pragma unroll
  for (int j = 0; j < 4; ++j) {
    int rowA = wm * 64 + j * 16 + lr;          // A0 half: rows 0-127
    aoffA[j] = rowA * 64 + ((kq ^ (rowA & 7)) << 3);
    int rowB = 128 + wm * 64 + j * 16 + lr;    // A1 half: rows 128-255
    aoffB[j] = rowB * 64 + ((kq ^ (rowB & 7)) << 3);
  }
#pragma unroll
  for (int g = 0; g < 2; ++g) {
    int row = wn * 32 + g * 16 + lr;
    boff[g] = row * 64 + ((kq ^ (row & 7)) << 3);
  }

  f32x4 acc1[8][2], acc2[8][2];
  f32x4 z = {0.f, 0.f, 0.f, 0.f};
#pragma unroll
  for (int f = 0; f < 8; ++f)
#pragma unroll
    for (int g = 0; g < 2; ++g) { acc1[f][g] = z; acc2[f][g] = z; }

  bf16x8 aA[4][2], aB[4][2], b1[2][2], b2[2][2];

  // prologue: stage t0 (8 rounds) + t1 (8); drain t0; pre-read aA(0), b1(0);
  // then BAR so the pre-reads are sampled before P1(0)'s stage can overwrite.
  STG1(gB1, 0, 0, sB1); STG1(gB1, 1, 0, sB1);
  STG1(gA, 0, 0, sA); STG1(gA, 1, 0, sA); STG1(gA, 2, 0, sA); STG1(gA, 3, 0, sA);
  STG1(gB2, 0, 0, sB2); STG1(gB2, 1, 0, sB2);
  STG1(gB1, 0, 64, sB1 + 8192); STG1(gB1, 1, 64, sB1 + 8192);
  STG1(gA, 0, 64, sA + 16384); STG1(gA, 1, 64, sA + 16384);
  STG1(gA, 2, 64, sA + 16384); STG1(gA, 3, 64, sA + 16384);
  STG1(gB2, 0, 64, sB2 + 8192); STG1(gB2, 1, 64, sB2 + 8192);
  asm volatile("s_waitcnt vmcnt(8)" ::: "memory");
  BAR;
#pragma unroll
  for (int j = 0; j < 4; ++j) {
    aA[j][0] = *(const bf16x8*)(sA + aoffA[j]);
    aA[j][1] = *(const bf16x8*)(sA + (aoffA[j] ^ 32));
  }
#pragma unroll
  for (int g = 0; g < 2; ++g) {
    b1[g][0] = *(const bf16x8*)(sB1 + boff[g]);
    b1[g][1] = *(const bf16x8*)(sB1 + (boff[g] ^ 32));
  }
  BAR;   // pre-reads sampled before first loop stage (r11 race fix)

  const int NT = D_DIM / 64;  // 32
  for (int t = 0; t < NT; ++t) {
    const int db = t & 1, nx = db ^ 1;
    const unsigned short* Acur  = sA  + db * 16384;
    const unsigned short* Anxt  = sA  + nx * 16384;
    const unsigned short* B1nxt = sB1 + nx * 8192;
    const unsigned short* B2cur = sB2 + db * 8192;
    unsigned short* AcurW  = (unsigned short*)sA  + db * 16384;
    unsigned short* B1curW = (unsigned short*)sB1 + db * 8192;
    unsigned short* B2curW = (unsigned short*)sB2 + db * 8192;
    const int p1ok = (t + 1 < NT), p2ok = (t + 2 < NT);
    const int tc2 = (t + 2) << 6;

    // ---- P1: read aB(t); stage B1(t+2); MFMA acc1 A0xB1 ----
#pragma unroll
    for (int j = 0; j < 4; ++j) {
      aB[j][0] = *(const bf16x8*)(Acur + aoffB[j]);
      aB[j][1] = *(const bf16x8*)(Acur + (aoffB[j] ^ 32));
    }
    if (p2ok) { STG1(gB1, 0, tc2, B1curW); STG1(gB1, 1, tc2, B1curW); }
    PRIO1;
#pragma unroll
    for (int j = 0; j < 4; ++j)
#pragma unroll
      for (int g = 0; g < 2; ++g) {
        acc1[j][g] = __builtin_amdgcn_mfma_f32_16x16x32_bf16(aA[j][0], b1[g][0], acc1[j][g], 0, 0, 0);
        acc1[j][g] = __builtin_amdgcn_mfma_f32_16x16x32_bf16(aA[j][1], b1[g][1], acc1[j][g], 0, 0, 0);
      }
    PRIO0;
    BAR;

    // ---- P2: read b2(t); stage A(t+2) r0-2; MFMA acc1 A1xB1; vmcnt ----
#pragma unroll
    for (int g = 0; g < 2; ++g) {
      b2[g][0] = *(const bf16x8*)(B2cur + boff[g]);
      b2[g][1] = *(const bf16x8*)(B2cur + (boff[g] ^ 32));
    }
    if (p2ok) { STG1(gA, 0, tc2, AcurW); STG1(gA, 1, tc2, AcurW); STG1(gA, 2, tc2, AcurW); }
    PRIO1;
#pragma unroll
    for (int j = 0; j < 4; ++j)
#pragma unroll
      for (int g = 0; g < 2; ++g) {
        acc1[4 + j][g] = __builtin_amdgcn_mfma_f32_16x16x32_bf16(aB[j][0], b1[g][0], acc1[4 + j][g], 0, 0, 0);
        acc1[4 + j][g] = __builtin_amdgcn_mfma_f32_16x16x32_bf16(aB[j][1], b1[g][1], acc1[4 + j][g], 0, 0, 0);
      }
    PRIO0;
    if (p2ok) { VMCNT5; } else if (p1ok) { VMCNT0; }   // tile t+1 fully landed
    BAR;

    // ---- P3: stage A(t+2) r3 + B2(t+2); MFMA acc2 A0xB2; read aA(t+1) ----
    if (p2ok) { STG1(gA, 3, tc2, AcurW); STG1(gB2, 0, tc2, B2curW); STG1(gB2, 1, tc2, B2curW); }
    PRIO1;
#pragma unroll
    for (int j = 0; j < 4; ++j)
#pragma unroll
      for (int g = 0; g < 2; ++g) {
        acc2[j][g] = __builtin_amdgcn_mfma_f32_16x16x32_bf16(aA[j][0], b2[g][0], acc2[j][g], 0, 0, 0);
        acc2[j][g] = __builtin_amdgcn_mfma_f32_16x16x32_bf16(aA[j][1], b2[g][1], acc2[j][g], 0, 0, 0);
      }
    PRIO0;
    if (p1ok) {
#pragma unroll
      for (int j = 0; j < 4; ++j) {
        aA[j][0] = *(const bf16x8*)(Anxt + aoffA[j]);
        aA[j][1] = *(const bf16x8*)(Anxt + (aoffA[j] ^ 32));
      }
    }
    BAR;

    // ---- P4: MFMA acc2 A1xB2; read b1(t+1) ----
    PRIO1;
#pragma unroll
    for (int j = 0; j < 4; ++j)
#pragma unroll
      for (int g = 0; g < 2; ++g) {
        acc2[4 + j][g] = __builtin_amdgcn_mfma_f32_16x16x32_bf16(aB[j][0], b2[g][0], acc2[4 + j][g], 0, 0, 0);
        acc2[4 + j][g] = __builtin_amdgcn_mfma_f32_16x16x32_bf16(aB[j][1], b2[g][1], acc2[4 + j][g], 0, 0, 0);
      }
    PRIO0;
    if (p1ok) {
#pragma unroll
      for (int g = 0; g < 2; ++g) {
        b1[g][0] = *(const bf16x8*)(B1nxt + boff[g]);
        b1[g][1] = *(const bf16x8*)(B1nxt + (boff[g] ^ 32));
      }
    }
    BAR;
  }

  // epilogue: h = silu(x1)*x2, bf16
#pragma unroll
  for (int f = 0; f < 8; ++f)
#pragma unroll
    for (int g = 0; g < 2; ++g)
#pragma unroll
      for (int r = 0; r < 4; ++r) {
        int row = m0 + (f >> 2) * 128 + wm * 64 + (f & 3) * 16 + kq * 4 + r;
        int col = n0 + wn * 32 + g * 16 + lr;
        float x1 = acc1[f][g][r], x2 = acc2[f][g][r];
        float hv = x1 / (1.f + __expf(-x1)) * x2;
        Hb[(long)row * FFN_DIM + col] = f2bf(hv);
      }
#undef STG1
}

// ---------- GEMM2 (r11-proven): read-ahead 4-phase, 256x128, BK=64 ----------
__global__ __launch_bounds__(512, 1) void gemm2(
    const unsigned short* __restrict__ Hb,    // (4096,8192)
    const unsigned short* __restrict__ W2T,   // (2048,8192)
    float* __restrict__ out) {                // (4096,2048)
  __shared__ __align__(16) unsigned short sA[2 * 16384];
  __shared__ __align__(16) unsigned short sB[2 * 8192];

  const int tid = threadIdx.x;
  const int wv = tid >> 6, l = tid & 63;
  const int wm = wv >> 1, wn = wv & 1;
  const int kq = l >> 4, lr = l & 15;
  const int bsw = (blockIdx.x & 7) * 32 + (blockIdx.x >> 3);
  const int m0 = (bsw >> 4) << 8;
  const int n0 = (bsw & 15) << 7;

  const int rsub = tid >> 3;
  const int sslot8 = ((tid & 7) ^ ((tid >> 3) & 7)) << 3;
  const unsigned short* gA = Hb  + (long)(m0 + rsub) * FFN_DIM + sslot8;
  const unsigned short* gB = W2T + (long)(n0 + rsub) * FFN_DIM + sslot8;

#define STG1(gbase, r_, tc_, lbase) \
  gload16((gbase) + (long)((r_) * 64) * FFN_DIM + (tc_), (lbase) + (r_) * 4096 + wv * 512)

  int aoff[4], boff[4];
#pragma unroll
  for (int f = 0; f < 4; ++f) {
    int row = wm * 64 + f * 16 + lr;
    aoff[f] = row * 64 + ((kq ^ (row & 7)) << 3);
  }
#pragma unroll
  for (int g = 0; g < 4; ++g) {
    int row = wn * 64 + g * 16 + lr;
    boff[g] = row * 64 + ((kq ^ (row & 7)) << 3);
  }

  f32x4 acc[4][4];
  f32x4 z = {0.f, 0.f, 0.f, 0.f};
#pragma unroll
  for (int f = 0; f < 4; ++f)
#pragma unroll
    for (int g = 0; g < 4; ++g) acc[f][g] = z;

  bf16x8 aA[2][2], aB[2][2], bA[2][2], bB[2][2];

  STG1(gB, 0, 0, sB); STG1(gB, 1, 0, sB);
  STG1(gA, 0, 0, sA); STG1(gA, 1, 0, sA); STG1(gA, 2, 0, sA); STG1(gA, 3, 0, sA);
  STG1(gB, 0, 64, sB + 8192); STG1(gB, 1, 64, sB + 8192);
  STG1(gA, 0, 64, sA + 16384); STG1(gA, 1, 64, sA + 16384);
  STG1(gA, 2, 64, sA + 16384); STG1(gA, 3, 64, sA + 16384);
  VMCNT6;
  BAR;
#pragma unroll
  for (int f = 0; f < 2; ++f) {
    aA[f][0] = *(const bf16x8*)(sA + aoff[f]);
    aA[f][1] = *(const bf16x8*)(sA + (aoff[f] ^ 32));
  }
#pragma unroll
  for (int g = 0; g < 2; ++g) {
    bA[g][0] = *(const bf16x8*)(sB + boff[g]);
    bA[g][1] = *(const bf16x8*)(sB + (boff[g] ^ 32));
  }
  BAR;   // pre-reads sampled before any loop stage (r11 race fix)

  const int NT = FFN_DIM / 64;  // 128
  for (int t = 0; t < NT; ++t) {
    const int db = t & 1, nx = db ^ 1;
    const unsigned short* Acur = sA + db * 16384;
    const unsigned short* Anxt = sA + nx * 16384;
    const unsigned short* Bcur = sB + db * 8192;
    const unsigned short* Bnxt = sB + nx * 8192;
    unsigned short* AcurW = (unsigned short*)sA + db * 16384;
    unsigned short* BcurW = (unsigned short*)sB + db * 8192;
    const int p1ok = (t + 1 < NT), p2ok = (t + 2 < NT);
    const int tc2 = (t + 2) << 6;

#pragma unroll
    for (int f = 0; f < 2; ++f) {
      aB[f][0] = *(const bf16x8*)(Acur + aoff[2 + f]);
      aB[f][1] = *(const bf16x8*)(Acur + (aoff[2 + f] ^ 32));
    }
#pragma unroll
    for (int g = 0; g < 2; ++g) {
      bB[g][0] = *(const bf16x8*)(Bcur + boff[2 + g]);
      bB[g][1] = *(const bf16x8*)(Bcur + (boff[2 + g] ^ 32));
    }
    PRIO1;
#pragma unroll
    for (int f = 0; f < 2; ++f)
#pragma unroll
      for (int g = 0; g < 2; ++g) {
        acc[f][g] = __builtin_amdgcn_mfma_f32_16x16x32_bf16(aA[f][0], bA[g][0], acc[f][g], 0, 0, 0);
        acc[f][g] = __builtin_amdgcn_mfma_f32_16x16x32_bf16(aA[f][1], bA[g][1], acc[f][g], 0, 0, 0);
      }
    PRIO0;
    BAR;

    if (p2ok) { STG1(gB, 0, tc2, BcurW); STG1(gB, 1, tc2, BcurW); STG1(gA, 0, tc2, AcurW); }
    PRIO1;
#pragma unroll
    for (int f = 0; f < 2; ++f)
#pragma unroll
      for (int g = 0; g < 2; ++g) {
        acc[2 + f][g] = __builtin_amdgcn_mfma_f32_16x16x32_bf16(aB[f][0], bA[g][0], acc[2 + f][g], 0, 0, 0);
        acc[2 + f][g] = __builtin_amdgcn_mfma_f32_16x16x32_bf16(aB[f][1], bA[g][1], acc[2 + f][g], 0, 0, 0);
      }
    PRIO0;
    if (p2ok) { VMCNT3; } else if (p1ok) { VMCNT0; }
    BAR;

    if (p2ok) { STG1(gA, 1, tc2, AcurW); STG1(gA, 2, tc2, AcurW); STG1(gA, 3, tc2, AcurW); }
    PRIO1;
#pragma unroll
    for (int f = 0; f < 2; ++f)
#pragma unroll
      for (int g = 0; g < 2; ++g) {
        acc[f][2 + g] = __builtin_amdgcn_mfma_f32_16x16x32_bf16(aA[f][0], bB[g][0], acc[f][2 + g], 0, 0, 0);
        acc[f][2 + g] = __builtin_amdgcn_mfma_f32_16x16x32_bf16(aA[f][1], bB[g][1], acc[f][2 + g], 0, 0, 0);
      }
    PRIO0;
    if (p1ok) {
#pragma unroll
      for (int f = 0; f < 2; ++f) {
        aA[f][0] = *(const bf16x8*)(Anxt + aoff[f]);
        aA[f][1] = *(const bf16x8*)(Anxt + (aoff[f] ^ 32));
      }
    }
    BAR;

    PRIO1;
#pragma unroll
    for (int f = 0; f < 2; ++f)
#pragma unroll
      for (int g = 0; g < 2; ++g) {
        acc[2 + f][2 + g] = __builtin_amdgcn_mfma_f32_16x16x32_bf16(aB[f][0], bB[g][0], acc[2 + f][2 + g], 0, 0, 0);
        acc[2 + f][2 + g] = __builtin_amdgcn_mfma_f32_16x16x32_bf16(aB[f][1], bB[g][1], acc[2 + f][2 + g], 0, 0, 0);
      }
    PRIO0;
    if (p1ok) {
#pragma unroll
      for (int g = 0; g < 2; ++g) {
        bA[g][0] = *(const bf16x8*)(Bnxt + boff[g]);
        bA[g][1] = *(const bf16x8*)(Bnxt + (boff[g] ^ 32));
      }
    }
    BAR;
  }

#pragma unroll
  for (int f = 0; f < 4; ++f)
#pragma unroll
    for (int g = 0; g < 4; ++g)
#pragma unroll
      for (int r = 0; r < 4; ++r) {
        int row = m0 + wm * 64 + f * 16 + kq * 4 + r;
        int col = n0 + wn * 64 + g * 16 + lr;
        out[(long)row * D_DIM + col] = acc[f][g][r];
      }
#undef STG1
}

extern "C" void kernel_launch(void* const* d_in, const int* in_sizes, int n_in,
                              void* d_out, int out_size, void* d_ws, size_t ws_size,
                              hipStream_t stream) {
  const float* x  = (const float*)d_in[0];
  const float* w1 = (const float*)d_in[1];
  const float* v1 = (const float*)d_in[2];
  const float* w2 = (const float*)d_in[3];
  const int* eidx = (const int*)d_in[4];

  char* ws = (char*)d_ws;
  unsigned short* Xb  = (unsigned short*)(ws);                  // 16 MiB
  unsigned short* W1b = (unsigned short*)(ws + (16l << 20));    // 32 MiB
  unsigned short* V1b = (unsigned short*)(ws + (48l << 20));    // 32 MiB
  unsigned short* W2T = (unsigned short*)(ws + (80l << 20));    // 32 MiB
  unsigned short* Hb  = (unsigned short*)(ws + (112l << 20));   // 64 MiB
  float* out = (float*)d_out;

  transpose_kernel<<<dim3(D_DIM / 64, FFN_DIM / 64), 512, 0, stream>>>(w2, eidx, W2T);
  convert3_kernel<<<dim3(2048, 3), 256, 0, stream>>>(x, w1, v1, eidx, Xb, W1b, V1b);
  gemm1_silu<<<1024, 512, 0, stream>>>(Xb, W1b, V1b, Hb);
  gemm2<<<256, 512, 0, stream>>>(Hb, W2T, out);
}